// Round 7
// baseline (140.478 us; speedup 1.0000x reference)
//
#include <hip/hip_runtime.h>

// Shape fixed by setup_inputs: B=4, L=4096, D=1024 (D re-derived at launch).
#define BB   4
#define LL   4096
#define KCH  8                   // boundaries per chunk (8 -> 2 blocks/CU in scan_out)
#define CMAX (LL / KCH)          // 512 worst-case chunks
#define EPSP 1e-4f

typedef float nfloat4 __attribute__((ext_vector_type(4)));  // native vec for nt-store

__device__ __forceinline__ void ema4(float4& h, float p, const float4 x) {
    h.x = fmaf(p, x.x - h.x, h.x);
    h.y = fmaf(p, x.y - h.y, h.y);
    h.z = fmaf(p, x.z - h.z, h.z);
    h.w = fmaf(p, x.w - h.w, h.w);
}

// ---------------- kernel 1: mask scan + publish metadata + local chunk scan ---
// grid = (CMAX, BB), block = 256. Each block scans its batch's full mask
// (16 KB, L2-resident) with a wave-level shfl scan; block c==0 additionally
// publishes nb/bpos/pk so k_scan_out never touches the mask again.
__global__ __launch_bounds__(256) void
k_chunk(const float4* __restrict__ X4, const float* __restrict__ bp,
        const int* __restrict__ mask,
        float4* __restrict__ U4, float* __restrict__ Adec,
        int* __restrict__ nb, int* __restrict__ bpos, float* __restrict__ pk,
        int D4) {
    __shared__ float sp[KCH];
    __shared__ int   wsum[4];
    const int c = blockIdx.x, b = blockIdx.y;
    const int tid  = threadIdx.x;
    const int base = tid * 16;                 // 256 thr x 16 tokens = LL
    int m[16];
    {
        const int4* mp = reinterpret_cast<const int4*>(mask + (size_t)b * LL + base);
        int4 v0 = mp[0], v1 = mp[1], v2 = mp[2], v3 = mp[3];
        m[0]=v0.x;  m[1]=v0.y;  m[2]=v0.z;  m[3]=v0.w;
        m[4]=v1.x;  m[5]=v1.y;  m[6]=v1.z;  m[7]=v1.w;
        m[8]=v2.x;  m[9]=v2.y;  m[10]=v2.z; m[11]=v2.w;
        m[12]=v3.x; m[13]=v3.y; m[14]=v3.z; m[15]=v3.w;
    }
    int cnt = 0;
#pragma unroll
    for (int i = 0; i < 16; ++i) cnt += (m[i] != 0);

    // wave-inclusive scan of per-thread counts (64-lane shfl, no barriers)
    const int lane = tid & 63, wid = tid >> 6;
    int incl = cnt;
#pragma unroll
    for (int off = 1; off < 64; off <<= 1) {
        int v = __shfl_up(incl, off, 64);
        if (lane >= off) incl += v;
    }
    if (lane == 63) wsum[wid] = incl;
    __syncthreads();
    const int n = wsum[0] + wsum[1] + wsum[2] + wsum[3];
    int k = incl - cnt;                        // exclusive prefix, this wave
    for (int w = 0; w < wid; ++w) k += wsum[w];

    const int k0 = c * KCH;
#pragma unroll
    for (int i = 0; i < 16; ++i) {
        if (m[i] != 0) {
            const int t = base + i;
            float p = bp[((size_t)(b * LL + t)) * 2 + 1];
            p = fminf(fmaxf(p, EPSP), 1.0f - EPSP);
            const int rel = k - k0;
            if (rel >= 0 && rel < KCH) sp[rel] = p;
            if (c == 0) {                      // publish (consecutive k per thread)
                pk[b * LL + k]          = p;
                bpos[b * (LL + 1) + k]  = t;
            }
            ++k;
        }
    }
    if (c == 0 && tid == 0) {
        nb[b] = n;
        bpos[b * (LL + 1) + n] = LL;           // tail sentinel
    }
    __syncthreads();

    if (k0 >= n) return;                       // uniform; after all barriers
    const int nk = (k0 + KCH < n) ? KCH : (n - k0);

    const float4* xp = X4 + (size_t)(b * LL + k0) * D4 + tid;
    float4 h = {0.f, 0.f, 0.f, 0.f};
    float  A = 1.0f;
    if (nk == KCH) {
#pragma unroll
        for (int kk = 0; kk < KCH; ++kk) {
            float p = sp[kk];
            ema4(h, p, xp[(size_t)kk * D4]);
            A *= (1.0f - p);
        }
    } else {
        for (int kk = 0; kk < nk; ++kk) {
            float p = sp[kk];
            ema4(h, p, xp[(size_t)kk * D4]);
            A *= (1.0f - p);
        }
    }
    U4[(size_t)(b * CMAX + c) * D4 + tid] = h;
    if (tid == 0) Adec[b * CMAX + c] = A;
}

// ---------------- kernel 2: lookback + rescan + direct segment stores ---------
// grid = (CMAX, BB). Inactive blocks (3/4) exit after one scalar load.
// X rows are L2-hot from k_chunk (same grid dims -> same block->XCD mapping).
// Output stores are nontemporal: out is never re-read, keep X/U in L2.
__global__ __launch_bounds__(256) void
k_scan_out(const float4* __restrict__ X4, const float4* __restrict__ U4,
           const float* __restrict__ Adec, const int* __restrict__ nb,
           const int* __restrict__ bpos, const float* __restrict__ pk,
           float4* __restrict__ out4, int D4) {
    const int c = blockIdx.x, b = blockIdx.y;
    const int n  = nb[b];
    const int k0 = c * KCH;
    if (k0 >= n) return;
    const int nk  = (k0 + KCH < n) ? KCH : (n - k0);
    const int tid = threadIdx.x;

    __shared__ float sp[KCH];
    __shared__ int   sb[KCH + 1];
    __shared__ float sA[CMAX];
    if (tid < nk)     sp[tid] = pk[b * LL + k0 + tid];
    if (tid < nk + 1) sb[tid] = bpos[b * (LL + 1) + k0 + tid];
    for (int i = tid; i < c; i += 256) sA[i] = Adec[b * CMAX + i];
    __syncthreads();

    // incoming state: recurrence over previous chunks' (A, U); U L2-resident
    float4 H = {0.f, 0.f, 0.f, 0.f};
    const float4* up = U4 + (size_t)b * CMAX * D4 + tid;
    for (int cc = 0; cc < c; ++cc) {
        float A = sA[cc];
        float4 u = up[(size_t)cc * D4];
        H.x = fmaf(A, H.x, u.x);
        H.y = fmaf(A, H.y, u.y);
        H.z = fmaf(A, H.z, u.z);
        H.w = fmaf(A, H.w, u.w);
    }

    const float4* xp = X4 + (size_t)(b * LL + k0) * D4 + tid;   // L2-hot
    nfloat4*      op = (nfloat4*)(out4 + (size_t)b * LL * D4 + tid);
    float4 h = H;
    for (int k = 0; k < nk; ++k) {
        float p = sp[k];
        ema4(h, p, xp[(size_t)k * D4]);
        nfloat4 hv = {h.x, h.y, h.z, h.w};
        const int t0 = sb[k], t1 = sb[k + 1];
        for (int t = t0; t < t1; ++t)
            __builtin_nontemporal_store(hv, op + (size_t)t * D4);  // 16 B/lane
    }
}

extern "C" void kernel_launch(void* const* d_in, const int* in_sizes, int n_in,
                              void* d_out, int out_size, void* d_ws, size_t ws_size,
                              hipStream_t stream) {
    const float* X    = (const float*)d_in[0];   // hidden_states (B,L,D) f32
    const float* bp   = (const float*)d_in[1];   // boundary_prob (B,L,2) f32
    const int*   mask = (const int*)d_in[2];     // boundary_mask (B,L)
    float*       out  = (float*)d_out;           // (B,L,D) f32

    const int D  = in_sizes[0] / in_sizes[2];    // 1024
    const int D4 = D / 4;

    // workspace carve (all offsets 16B-aligned; total ~8.2 MiB of 256 MiB)
    char* w = (char*)d_ws;
    int*   nb   = (int*)w;   w += 256;
    int*   bpos = (int*)w;   w += 65568;                           // BB*(LL+1)*4 padded
    float* pk   = (float*)w; w += sizeof(float) * BB * LL;         // 65536
    float* Adec = (float*)w; w += sizeof(float) * BB * CMAX;       // 8192
    float* U    = (float*)w;                                       // BB*CMAX*D*4 = 8 MiB

    dim3 grid(CMAX, BB);
    k_chunk<<<grid, 256, 0, stream>>>((const float4*)X, bp, mask,
                                      (float4*)U, Adec, nb, bpos, pk, D4);
    k_scan_out<<<grid, 256, 0, stream>>>((const float4*)X, (const float4*)U,
                                         Adec, nb, bpos, pk,
                                         (float4*)out, D4);
}

// Round 8
// 135.347 us; speedup vs baseline: 1.0379x; 1.0379x over previous
//
#include <hip/hip_runtime.h>

// Shape fixed by setup_inputs: B=4, L=4096, D=1024 (D re-derived at launch).
#define BB   4
#define LL   4096
#define KCH  16                  // boundaries per chunk
#define CMAX (LL / KCH)          // 256 worst-case chunks (all tokens boundaries)
#define EPSP 1e-4f

__device__ __forceinline__ void ema4(float4& h, float p, const float4 x) {
    h.x = fmaf(p, x.x - h.x, h.x);
    h.y = fmaf(p, x.y - h.y, h.y);
    h.z = fmaf(p, x.z - h.z, h.z);
    h.w = fmaf(p, x.w - h.w, h.w);
}

// Block-local boundary extraction. Every block scans its batch's full mask
// (16 KB, L2-resident) with a wave-level shfl scan and fills LDS with the
// probs (and, if NEED_POS, token positions + sentinel) for its own chunk.
// Returns total boundary count n. All threads participate (no divergence
// around barriers); caller early-outs AFTER this returns.
template <bool NEED_POS>
__device__ __forceinline__ int extract(const float* __restrict__ bp,
                                       const int* __restrict__ mask,
                                       int b, int c,
                                       float* sp, int* sb, int* wsum) {
    const int tid  = threadIdx.x;
    const int base = tid * 16;                 // 256 thr x 16 tokens = LL
    int m[16];
    {
        const int4* mp = reinterpret_cast<const int4*>(mask + (size_t)b * LL + base);
        int4 v0 = mp[0], v1 = mp[1], v2 = mp[2], v3 = mp[3];
        m[0]=v0.x;  m[1]=v0.y;  m[2]=v0.z;  m[3]=v0.w;
        m[4]=v1.x;  m[5]=v1.y;  m[6]=v1.z;  m[7]=v1.w;
        m[8]=v2.x;  m[9]=v2.y;  m[10]=v2.z; m[11]=v2.w;
        m[12]=v3.x; m[13]=v3.y; m[14]=v3.z; m[15]=v3.w;
    }
    int cnt = 0;
#pragma unroll
    for (int i = 0; i < 16; ++i) cnt += (m[i] != 0);

    // wave-inclusive scan of per-thread counts (64-lane shfl, no barriers)
    const int lane = tid & 63, wid = tid >> 6;
    int incl = cnt;
#pragma unroll
    for (int off = 1; off < 64; off <<= 1) {
        int v = __shfl_up(incl, off, 64);
        if (lane >= off) incl += v;
    }
    if (lane == 63) wsum[wid] = incl;
    __syncthreads();
    const int n = wsum[0] + wsum[1] + wsum[2] + wsum[3];
    int k = incl - cnt;                        // exclusive prefix, this wave
    for (int w = 0; w < wid; ++w) k += wsum[w];

    const int k0 = c * KCH;
#pragma unroll
    for (int i = 0; i < 16; ++i) {
        if (m[i] != 0) {
            const int rel = k - k0;
            if (rel >= 0 && rel < KCH) {
                float p = bp[((size_t)(b * LL + base + i)) * 2 + 1];
                sp[rel] = fminf(fmaxf(p, EPSP), 1.0f - EPSP);
                if constexpr (NEED_POS) sb[rel] = base + i;
            } else if (rel == KCH) {
                if constexpr (NEED_POS) sb[KCH] = base + i;  // next-chunk sentinel
            }
            ++k;
        }
    }
    if constexpr (NEED_POS) {
        if (tid == 0 && k0 < n && k0 + KCH >= n) sb[n - k0] = LL;  // tail sentinel
    }
    __syncthreads();
    return n;
}

// ---------------- kernel 1: per-chunk local scan -> U[b,c,:], Adec[b,c] --------
// grid = (CMAX, B), block = 256, one float4 (4 channels) per thread.
__global__ __launch_bounds__(256) void
k_chunk(const float4* __restrict__ X4, const float* __restrict__ bp,
        const int* __restrict__ mask,
        float4* __restrict__ U4, float* __restrict__ Adec,
        int* __restrict__ nb, int D4) {
    __shared__ float sp[KCH];
    __shared__ int   wsum[4];
    const int c = blockIdx.x, b = blockIdx.y;
    const int n = extract<false>(bp, mask, b, c, sp, nullptr, wsum);
    if (c == 0 && threadIdx.x == 0) nb[b] = n;   // publish count for k_prefix
    const int k0 = c * KCH;
    if (k0 >= n) return;
    const int nk  = (k0 + KCH < n) ? KCH : (n - k0);
    const int tid = threadIdx.x;

    const float4* xp = X4 + (size_t)(b * LL + k0) * D4 + tid;
    float4 h = {0.f, 0.f, 0.f, 0.f};
    float  A = 1.0f;
    if (nk == KCH) {
#pragma unroll
        for (int k = 0; k < KCH; ++k) {
            float p = sp[k];
            ema4(h, p, xp[(size_t)k * D4]);
            A *= (1.0f - p);
        }
    } else {
        for (int k = 0; k < nk; ++k) {
            float p = sp[k];
            ema4(h, p, xp[(size_t)k * D4]);
            A *= (1.0f - p);
        }
    }
    U4[(size_t)(b * CMAX + c) * D4 + tid] = h;
    if (tid == 0) Adec[b * CMAX + c] = A;
}

// ---------------- kernel 2 (NEW): O(C) exclusive prefix over chunk states -----
// grid = BB, block = 256. Folds <=64 active chunks per batch once, writing the
// incoming state Hin[b,c,:] for every chunk. Same fold order as R2's per-block
// lookback -> bit-identical arithmetic, but U is read ONCE (1 MB) instead of
// O(C^2)/2 times (32 MB).
__global__ __launch_bounds__(256) void
k_prefix(const float4* __restrict__ U4, const float* __restrict__ Adec,
         const int* __restrict__ nb, float4* __restrict__ Hin4, int D4) {
    const int b   = blockIdx.x;
    const int tid = threadIdx.x;
    const int n    = nb[b];
    const int Cact = (n + KCH - 1) / KCH;
    __shared__ float sA[CMAX];
    for (int i = tid; i < Cact; i += 256) sA[i] = Adec[b * CMAX + i];
    __syncthreads();
    for (int g = tid; g < D4; g += 256) {
        const float4* up = U4   + (size_t)b * CMAX * D4 + g;
        float4*       hp = Hin4 + (size_t)b * CMAX * D4 + g;
        float4 H = {0.f, 0.f, 0.f, 0.f};
        for (int c = 0; c < Cact; ++c) {
            hp[(size_t)c * D4] = H;            // exclusive: state BEFORE chunk c
            float A  = sA[c];
            float4 u = up[(size_t)c * D4];
            H.x = fmaf(A, H.x, u.x);
            H.y = fmaf(A, H.y, u.y);
            H.z = fmaf(A, H.z, u.z);
            H.w = fmaf(A, H.w, u.w);
        }
    }
}

// ---------------- kernel 3: local rescan from Hin + segment stores ------------
// Identical to R2's k_scan_out except the lookback loop is replaced by one
// 16 B/lane read of this chunk's precomputed incoming state.
__global__ __launch_bounds__(256) void
k_scan_out(const float4* __restrict__ X4, const float* __restrict__ bp,
           const int* __restrict__ mask, const float4* __restrict__ Hin4,
           float4* __restrict__ out4, int D4) {
    __shared__ float sp[KCH];
    __shared__ int   sb[KCH + 1];
    __shared__ int   wsum[4];
    const int c = blockIdx.x, b = blockIdx.y;
    const int n = extract<true>(bp, mask, b, c, sp, sb, wsum);
    const int k0 = c * KCH;
    if (k0 >= n) return;
    const int nk  = (k0 + KCH < n) ? KCH : (n - k0);
    const int tid = threadIdx.x;

    float4 h = Hin4[(size_t)(b * CMAX + c) * D4 + tid];   // incoming state

    const float4* xp = X4 + (size_t)(b * LL + k0) * D4 + tid;
    float4*       op = out4 + (size_t)b * LL * D4 + tid;
    for (int k = 0; k < nk; ++k) {
        float p = sp[k];
        ema4(h, p, xp[(size_t)k * D4]);          // X rows L2-hot from kernel 1
        const int t0 = sb[k], t1 = sb[k + 1];
        for (int t = t0; t < t1; ++t)
            op[(size_t)t * D4] = h;              // 16 B/lane, coalesced across block
    }
}

extern "C" void kernel_launch(void* const* d_in, const int* in_sizes, int n_in,
                              void* d_out, int out_size, void* d_ws, size_t ws_size,
                              hipStream_t stream) {
    const float* X    = (const float*)d_in[0];   // hidden_states (B,L,D) f32
    const float* bp   = (const float*)d_in[1];   // boundary_prob (B,L,2) f32
    const int*   mask = (const int*)d_in[2];     // boundary_mask (B,L)
    float*       out  = (float*)d_out;           // (B,L,D) f32

    const int D  = in_sizes[0] / in_sizes[2];    // 1024
    const int D4 = D / 4;

    // workspace carve (16B-aligned; total ~8.3 MiB of 256 MiB)
    char* w = (char*)d_ws;
    int*   nb   = (int*)w;   w += 256;
    float* Adec = (float*)w; w += sizeof(float) * BB * CMAX;       // 4 KB
    float* U    = (float*)w; w += sizeof(float) * BB * CMAX * D;   // 4 MiB
    float* Hin  = (float*)w;                                       // 4 MiB

    dim3 grid(CMAX, BB);
    k_chunk<<<grid, 256, 0, stream>>>((const float4*)X, bp, mask,
                                      (float4*)U, Adec, nb, D4);
    k_prefix<<<BB, 256, 0, stream>>>((const float4*)U, Adec, nb,
                                     (float4*)Hin, D4);
    k_scan_out<<<grid, 256, 0, stream>>>((const float4*)X, bp, mask,
                                         (const float4*)Hin,
                                         (float4*)out, D4);
}